// Round 6
// baseline (639.651 us; speedup 1.0000x reference)
//
#include <hip/hip_runtime.h>

#define NN 50000
#define NE 800000
#define DD 128

typedef __attribute__((ext_vector_type(8))) short short8;
typedef __attribute__((ext_vector_type(4))) float f32x4;

__device__ inline unsigned short f2bf_rne(float f) {
  unsigned u = __float_as_uint(f);
  u += 0x7FFF + ((u >> 16) & 1);
  return (unsigned short)(u >> 16);
}
__device__ inline float bf2f(unsigned short h) {
  return __uint_as_float(((unsigned)h) << 16);
}

// ------------------------------------------------- CSR build: histogram
__global__ __launch_bounds__(256) void hist_dst(const int* __restrict__ dst,
                                                int* __restrict__ cnt) {
  int e = blockIdx.x * 256 + threadIdx.x;
  if (e < NE) atomicAdd(&cnt[dst[e]], 1);
}

// ------------------------------------------------- CSR build: scan (1 block)
__global__ __launch_bounds__(1024) void scan_nodes(const int* __restrict__ cnt,
                                                   int* __restrict__ offs,
                                                   int* __restrict__ cursor) {
  __shared__ int wsum[16];
  __shared__ int wpre[16];
  const int t = threadIdx.x;
  const int lane = t & 63, wv = t >> 6;
  int carry = 0;
  for (int base = 0; base < NN; base += 8192) {
    const int i0 = base + t * 8;
    int4 a = make_int4(0, 0, 0, 0), b = make_int4(0, 0, 0, 0);
    if (i0 + 8 <= NN) {
      a = *(const int4*)(cnt + i0);
      b = *(const int4*)(cnt + i0 + 4);
    } else if (i0 < NN) {
      int tmp[8];
      for (int j = 0; j < 8; ++j) tmp[j] = (i0 + j < NN) ? cnt[i0 + j] : 0;
      a = make_int4(tmp[0], tmp[1], tmp[2], tmp[3]);
      b = make_int4(tmp[4], tmp[5], tmp[6], tmp[7]);
    }
    const int own = a.x + a.y + a.z + a.w + b.x + b.y + b.z + b.w;
    int inc = own;
#pragma unroll
    for (int d = 1; d < 64; d <<= 1) {
      int v = __shfl_up(inc, d, 64);
      if (lane >= d) inc += v;
    }
    if (lane == 63) wsum[wv] = inc;
    __syncthreads();
    if (t < 16) {
      int v = wsum[t];
      int p = v;
#pragma unroll
      for (int d = 1; d < 16; d <<= 1) {
        int u = __shfl_up(p, d, 16);
        if (t >= d) p += u;
      }
      wpre[t] = p - v;
      if (t == 15) wsum[15] = p;
    }
    __syncthreads();
    int run = carry + wpre[wv] + inc - own;
    const int o0 = run,      o1 = o0 + a.x, o2 = o1 + a.y, o3 = o2 + a.z;
    const int o4 = o3 + a.w, o5 = o4 + b.x, o6 = o5 + b.y, o7 = o6 + b.z;
    if (i0 + 8 <= NN) {
      *(int4*)(offs + i0)       = make_int4(o0, o1, o2, o3);
      *(int4*)(offs + i0 + 4)   = make_int4(o4, o5, o6, o7);
      *(int4*)(cursor + i0)     = make_int4(o0, o1, o2, o3);
      *(int4*)(cursor + i0 + 4) = make_int4(o4, o5, o6, o7);
    } else if (i0 < NN) {
      const int o[8] = {o0, o1, o2, o3, o4, o5, o6, o7};
      for (int j = 0; j < 8; ++j)
        if (i0 + j < NN) { offs[i0 + j] = o[j]; cursor[i0 + j] = o[j]; }
    }
    carry += wsum[15];
    __syncthreads();
  }
  if (t == 0) offs[NN] = carry;
}

// ------------------------------------------------- CSR build: fill
__global__ __launch_bounds__(256) void csr_fill(
    const int* __restrict__ src, const int* __restrict__ dst,
    const float* __restrict__ ea, int* __restrict__ cursor,
    int* __restrict__ srcs_s, float* __restrict__ eas_s,
    int* __restrict__ eid_s) {
  int e = blockIdx.x * 256 + threadIdx.x;
  if (e >= NE) return;
  int pos = atomicAdd(&cursor[dst[e]], 1);
  srcs_s[pos] = src[e];
  eas_s[pos] = ea[e];
  eid_s[pos] = e;
}

// ------------------------------------------------- weight prep: transpose + split
// 8 mats [128k][128n] f32 -> WT_hi/WT_lo [g][n][k] bf16
__global__ __launch_bounds__(256) void prep_w(
    const float* __restrict__ Wl1, const float* __restrict__ Wl2,
    const float* __restrict__ Wp1,
    unsigned short* __restrict__ WTh, unsigned short* __restrict__ WTl) {
  int tid = blockIdx.x * 256 + threadIdx.x;  // 8 * 16384
  if (tid >= 8 * 16384) return;
  int g = tid >> 14, idx = tid & 16383;
  int n = idx >> 7, k = idx & 127;
  const float* s;
  if (g < 3) s = Wl1 + (size_t)g * 16384;
  else if (g < 6) s = Wl2 + (size_t)(g - 3) * 16384;
  else s = Wp1 + (size_t)(g - 6) * 16384;
  float v = s[k * 128 + n];
  unsigned short hi = f2bf_rne(v);
  WTh[tid] = hi;
  WTl[tid] = f2bf_rne(v - bf2f(hi));
}

// ------------------------------------------------- per-node aggregation
__global__ __launch_bounds__(256) void aggregate(
    const float* __restrict__ x, const int* __restrict__ offs,
    const int* __restrict__ srcs_s, const float* __restrict__ eas_s,
    const float4* __restrict__ We4, const float4* __restrict__ be4,
    float* __restrict__ out) {
  const int slot = threadIdx.x >> 5, lane = threadIdx.x & 31;
  const int n = blockIdx.x * 8 + slot;
  if (n >= NN) return;
  const float4 wv = We4[lane], bv = be4[lane];
  float4 acc0 = ((const float4*)(x + (size_t)n * DD))[lane];
  float4 acc1 = make_float4(0.f, 0.f, 0.f, 0.f);
  const int beg = offs[n], end = offs[n + 1];
  int i = beg;
  for (; i + 2 <= end; i += 2) {
    const int s0 = srcs_s[i], s1 = srcs_s[i + 1];
    const float a0 = eas_s[i], a1 = eas_s[i + 1];
    const float4 x0 = ((const float4*)(x + (size_t)s0 * DD))[lane];
    const float4 x1 = ((const float4*)(x + (size_t)s1 * DD))[lane];
    acc0.x += fmaxf(fmaf(a0, wv.x, bv.x) + x0.x, 0.f);
    acc0.y += fmaxf(fmaf(a0, wv.y, bv.y) + x0.y, 0.f);
    acc0.z += fmaxf(fmaf(a0, wv.z, bv.z) + x0.z, 0.f);
    acc0.w += fmaxf(fmaf(a0, wv.w, bv.w) + x0.w, 0.f);
    acc1.x += fmaxf(fmaf(a1, wv.x, bv.x) + x1.x, 0.f);
    acc1.y += fmaxf(fmaf(a1, wv.y, bv.y) + x1.y, 0.f);
    acc1.z += fmaxf(fmaf(a1, wv.z, bv.z) + x1.z, 0.f);
    acc1.w += fmaxf(fmaf(a1, wv.w, bv.w) + x1.w, 0.f);
  }
  if (i < end) {
    const int s0 = srcs_s[i];
    const float a0 = eas_s[i];
    const float4 x0 = ((const float4*)(x + (size_t)s0 * DD))[lane];
    acc0.x += fmaxf(fmaf(a0, wv.x, bv.x) + x0.x, 0.f);
    acc0.y += fmaxf(fmaf(a0, wv.y, bv.y) + x0.y, 0.f);
    acc0.z += fmaxf(fmaf(a0, wv.z, bv.z) + x0.z, 0.f);
    acc0.w += fmaxf(fmaf(a0, wv.w, bv.w) + x0.w, 0.f);
  }
  acc0.x += acc1.x; acc0.y += acc1.y; acc0.z += acc1.z; acc0.w += acc1.w;
  ((float4*)(out + (size_t)n * DD))[lane] = acc0;
}

// ------------------------------------------------- fused MLP via split-bf16 MFMA
// out = relu(relu(in@W1+b1)@W2+b2). 64 rows/block, 4 waves, wave = 16 rows.
// A f32->hi/lo in-reg; B from pre-split WT (global, L2-resident).
// h handoff through per-wave-private LDS stripe: ZERO barriers.
// In-place safe: each block touches only its own 64 rows.
__global__ __launch_bounds__(256) void fused_mlp_mfma(
    const float* __restrict__ in,
    const unsigned short* __restrict__ W1h, const unsigned short* __restrict__ W1l,
    const unsigned short* __restrict__ W2h, const unsigned short* __restrict__ W2l,
    const float* __restrict__ b1, const float* __restrict__ b2,
    float* __restrict__ out) {
  __shared__ float hbuf[64][132];
  const int t = threadIdx.x;
  const int w = t >> 6, l = t & 63;
  const int lr = l & 15;      // row-in-16 (A) / col-in-16 (B,C)
  const int kg = l >> 4;      // k-group 0..3
  const int row0 = blockIdx.x * 64 + w * 16;
  const int myrow = row0 + lr;

  f32x4 acc[8];
#pragma unroll
  for (int i = 0; i < 8; ++i) acc[i] = (f32x4){0.f, 0.f, 0.f, 0.f};

  // ---------------- GEMM1 (A from global f32)
#pragma unroll
  for (int ks = 0; ks < 4; ++ks) {
    const int k0 = ks * 32 + kg * 8;
    float av[8];
    if (myrow < NN) {
      const float* ap = in + (size_t)myrow * DD + k0;
      *(float4*)&av[0] = *(const float4*)ap;
      *(float4*)&av[4] = *(const float4*)(ap + 4);
    } else {
#pragma unroll
      for (int j = 0; j < 8; ++j) av[j] = 0.f;
    }
    short8 ah, al;
#pragma unroll
    for (int j = 0; j < 8; ++j) {
      unsigned short h = f2bf_rne(av[j]);
      ah[j] = (short)h;
      al[j] = (short)f2bf_rne(av[j] - bf2f(h));
    }
#pragma unroll
    for (int tile = 0; tile < 8; ++tile) {
      const size_t bo = (size_t)(tile * 16 + lr) * DD + k0;
      short8 bh = *(const short8*)(W1h + bo);
      short8 bl = *(const short8*)(W1l + bo);
      acc[tile] = __builtin_amdgcn_mfma_f32_16x16x32_bf16(ah, bh, acc[tile], 0, 0, 0);
      acc[tile] = __builtin_amdgcn_mfma_f32_16x16x32_bf16(ah, bl, acc[tile], 0, 0, 0);
      acc[tile] = __builtin_amdgcn_mfma_f32_16x16x32_bf16(al, bh, acc[tile], 0, 0, 0);
    }
  }

  // h = relu(acc+b1) -> own wave's LDS stripe (rows w*16..w*16+15)
#pragma unroll
  for (int tile = 0; tile < 8; ++tile) {
    const int col = tile * 16 + lr;
    const float bb = b1[col];
#pragma unroll
    for (int q = 0; q < 4; ++q) {
      hbuf[w * 16 + kg * 4 + q][col] = fmaxf(acc[tile][q] + bb, 0.f);
    }
    acc[tile] = (f32x4){0.f, 0.f, 0.f, 0.f};
  }

  // ---------------- GEMM2 (A from LDS stripe; no barrier: wave reads own rows)
#pragma unroll
  for (int ks = 0; ks < 4; ++ks) {
    const int k0 = ks * 32 + kg * 8;
    float av[8];
    *(float4*)&av[0] = *(const float4*)&hbuf[w * 16 + lr][k0];
    *(float4*)&av[4] = *(const float4*)&hbuf[w * 16 + lr][k0 + 4];
    short8 ah, al;
#pragma unroll
    for (int j = 0; j < 8; ++j) {
      unsigned short h = f2bf_rne(av[j]);
      ah[j] = (short)h;
      al[j] = (short)f2bf_rne(av[j] - bf2f(h));
    }
#pragma unroll
    for (int tile = 0; tile < 8; ++tile) {
      const size_t bo = (size_t)(tile * 16 + lr) * DD + k0;
      short8 bh = *(const short8*)(W2h + bo);
      short8 bl = *(const short8*)(W2l + bo);
      acc[tile] = __builtin_amdgcn_mfma_f32_16x16x32_bf16(ah, bh, acc[tile], 0, 0, 0);
      acc[tile] = __builtin_amdgcn_mfma_f32_16x16x32_bf16(ah, bl, acc[tile], 0, 0, 0);
      acc[tile] = __builtin_amdgcn_mfma_f32_16x16x32_bf16(al, bh, acc[tile], 0, 0, 0);
    }
  }

  // epilogue: relu(acc+b2) -> global (C layout: col=lane&15, row=(lane>>4)*4+q)
#pragma unroll
  for (int tile = 0; tile < 8; ++tile) {
    const int col = tile * 16 + lr;
    const float bb = b2[col];
#pragma unroll
    for (int q = 0; q < 4; ++q) {
      const int r = row0 + kg * 4 + q;
      if (r < NN) out[(size_t)r * DD + col] = fmaxf(acc[tile][q] + bb, 0.f);
    }
  }
}

// ------------------------------------------------- predictor GEMMs via MFMA
// P1 = xf@Wp1[:128]; P2 = xf@Wp1[128:] + bp1. No LDS, no barriers.
__global__ __launch_bounds__(256) void gemm_pred_mfma(
    const float* __restrict__ in,
    const unsigned short* __restrict__ Wah, const unsigned short* __restrict__ Wal,
    const unsigned short* __restrict__ Wbh, const unsigned short* __restrict__ Wbl,
    const float* __restrict__ bp1,
    float* __restrict__ P1, float* __restrict__ P2) {
  const int t = threadIdx.x;
  const int w = t >> 6, l = t & 63;
  const int lr = l & 15, kg = l >> 4;
  const int row0 = blockIdx.x * 64 + w * 16;
  const int myrow = row0 + lr;

  f32x4 accA[8], accB[8];
#pragma unroll
  for (int i = 0; i < 8; ++i) {
    accA[i] = (f32x4){0.f, 0.f, 0.f, 0.f};
    accB[i] = (f32x4){0.f, 0.f, 0.f, 0.f};
  }

#pragma unroll
  for (int ks = 0; ks < 4; ++ks) {
    const int k0 = ks * 32 + kg * 8;
    float av[8];
    if (myrow < NN) {
      const float* ap = in + (size_t)myrow * DD + k0;
      *(float4*)&av[0] = *(const float4*)ap;
      *(float4*)&av[4] = *(const float4*)(ap + 4);
    } else {
#pragma unroll
      for (int j = 0; j < 8; ++j) av[j] = 0.f;
    }
    short8 ah, al;
#pragma unroll
    for (int j = 0; j < 8; ++j) {
      unsigned short h = f2bf_rne(av[j]);
      ah[j] = (short)h;
      al[j] = (short)f2bf_rne(av[j] - bf2f(h));
    }
#pragma unroll
    for (int tile = 0; tile < 8; ++tile) {
      const size_t bo = (size_t)(tile * 16 + lr) * DD + k0;
      short8 bh = *(const short8*)(Wah + bo);
      short8 bl = *(const short8*)(Wal + bo);
      accA[tile] = __builtin_amdgcn_mfma_f32_16x16x32_bf16(ah, bh, accA[tile], 0, 0, 0);
      accA[tile] = __builtin_amdgcn_mfma_f32_16x16x32_bf16(ah, bl, accA[tile], 0, 0, 0);
      accA[tile] = __builtin_amdgcn_mfma_f32_16x16x32_bf16(al, bh, accA[tile], 0, 0, 0);
      short8 ch = *(const short8*)(Wbh + bo);
      short8 cl = *(const short8*)(Wbl + bo);
      accB[tile] = __builtin_amdgcn_mfma_f32_16x16x32_bf16(ah, ch, accB[tile], 0, 0, 0);
      accB[tile] = __builtin_amdgcn_mfma_f32_16x16x32_bf16(ah, cl, accB[tile], 0, 0, 0);
      accB[tile] = __builtin_amdgcn_mfma_f32_16x16x32_bf16(al, ch, accB[tile], 0, 0, 0);
    }
  }

#pragma unroll
  for (int tile = 0; tile < 8; ++tile) {
    const int col = tile * 16 + lr;
    const float bb = bp1[col];
#pragma unroll
    for (int q = 0; q < 4; ++q) {
      const int r = row0 + kg * 4 + q;
      if (r < NN) {
        P1[(size_t)r * DD + col] = accA[tile][q];
        P2[(size_t)r * DD + col] = accB[tile][q] + bb;
      }
    }
  }
}

// ------------------------------------------------- final edge pass (node-parallel)
__global__ __launch_bounds__(256) void edge_out(
    const float4* __restrict__ P1_4, const float4* __restrict__ P2_4,
    const int* __restrict__ offs, const int* __restrict__ srcs_s,
    const int* __restrict__ eid_s, const float4* __restrict__ Wp2_4,
    const float* __restrict__ bp2, float* __restrict__ out) {
  const int slot = threadIdx.x >> 5, lane = threadIdx.x & 31;
  const int n = blockIdx.x * 8 + slot;
  if (n >= NN) return;
  const float4 p2 = P2_4[(size_t)n * 32 + lane];
  const float4 w = Wp2_4[lane];
  const float bb = bp2[0];
  const int beg = offs[n], end = offs[n + 1];
  int i = beg;
  for (; i + 2 <= end; i += 2) {
    const int s0 = srcs_s[i], s1 = srcs_s[i + 1];
    const int e0 = eid_s[i], e1 = eid_s[i + 1];
    const float4 q0 = P1_4[(size_t)s0 * 32 + lane];
    const float4 q1 = P1_4[(size_t)s1 * 32 + lane];
    float v0 = fmaxf(q0.x + p2.x, 0.f) * w.x + fmaxf(q0.y + p2.y, 0.f) * w.y
             + fmaxf(q0.z + p2.z, 0.f) * w.z + fmaxf(q0.w + p2.w, 0.f) * w.w;
    float v1 = fmaxf(q1.x + p2.x, 0.f) * w.x + fmaxf(q1.y + p2.y, 0.f) * w.y
             + fmaxf(q1.z + p2.z, 0.f) * w.z + fmaxf(q1.w + p2.w, 0.f) * w.w;
#pragma unroll
    for (int m = 16; m >= 1; m >>= 1) {
      v0 += __shfl_xor(v0, m, 64);
      v1 += __shfl_xor(v1, m, 64);
    }
    if (lane == 0) { out[e0] = v0 + bb; out[e1] = v1 + bb; }
  }
  if (i < end) {
    const int s0 = srcs_s[i];
    const int e0 = eid_s[i];
    const float4 q0 = P1_4[(size_t)s0 * 32 + lane];
    float v0 = fmaxf(q0.x + p2.x, 0.f) * w.x + fmaxf(q0.y + p2.y, 0.f) * w.y
             + fmaxf(q0.z + p2.z, 0.f) * w.z + fmaxf(q0.w + p2.w, 0.f) * w.w;
#pragma unroll
    for (int m = 16; m >= 1; m >>= 1) v0 += __shfl_xor(v0, m, 64);
    if (lane == 0) out[e0] = v0 + bb;
  }
}

// ---------------------------------------------------------------- launch
extern "C" void kernel_launch(void* const* d_in, const int* in_sizes, int n_in,
                              void* d_out, int out_size, void* d_ws, size_t ws_size,
                              hipStream_t stream) {
  const float* x_in = (const float*)d_in[0];
  const float* ea   = (const float*)d_in[1];
  const int*   ei   = (const int*)d_in[2];   // integer inputs arrive as int32
  const float* Wl1 = (const float*)d_in[3];
  const float* bl1 = (const float*)d_in[4];
  const float* Wl2 = (const float*)d_in[5];
  const float* bl2 = (const float*)d_in[6];
  const float* We  = (const float*)d_in[7];
  const float* be  = (const float*)d_in[8];
  const float* Wp1 = (const float*)d_in[9];
  const float* bp1 = (const float*)d_in[10];
  const float* Wp2 = (const float*)d_in[11];
  const float* bp2 = (const float*)d_in[12];
  const int* src = ei;
  const int* dst = ei + NE;

  // workspace layout (~62 MB)
  float* bufA   = (float*)d_ws;                    // NN*DD
  float* bufB   = bufA + (size_t)NN * DD;          // NN*DD
  int*   cnt    = (int*)(bufB + (size_t)NN * DD);  // NN
  int*   offs   = cnt + NN;                        // NN+1
  int*   cursor = offs + NN + 1;                   // NN
  int*   srcs_s = cursor + NN;                     // NE
  float* eas_s  = (float*)(srcs_s + NE);           // NE
  int*   eid_s  = (int*)(eas_s + NE);              // NE
  unsigned short* WTh = (unsigned short*)(eid_s + NE);  // 8*16384 bf16
  unsigned short* WTl = WTh + 8 * 16384;                // 8*16384 bf16

  // CSR build + weight prep (per-launch, deterministic)
  hipMemsetAsync(cnt, 0, NN * sizeof(int), stream);
  hist_dst<<<NE / 256, 256, 0, stream>>>(dst, cnt);
  scan_nodes<<<1, 1024, 0, stream>>>(cnt, offs, cursor);
  csr_fill<<<NE / 256, 256, 0, stream>>>(src, dst, ea, cursor, srcs_s, eas_s, eid_s);
  prep_w<<<(8 * 16384 + 255) / 256, 256, 0, stream>>>(Wl1, Wl2, Wp1, WTh, WTl);

  const int mfmaBlocks = (NN + 63) / 64;
  const int aggBlocks = (NN + 7) / 8;
  const float* xl = x_in;
  float* bufs[2] = {bufA, bufB};
  for (int l = 0; l < 3; ++l) {
    float* cur = bufs[l & 1];
    aggregate<<<aggBlocks, 256, 0, stream>>>(
        xl, offs, srcs_s, eas_s, (const float4*)(We + l * DD),
        (const float4*)(be + l * DD), cur);
    fused_mlp_mfma<<<mfmaBlocks, 256, 0, stream>>>(
        cur,
        WTh + (size_t)l * 16384, WTl + (size_t)l * 16384,
        WTh + (size_t)(3 + l) * 16384, WTl + (size_t)(3 + l) * 16384,
        bl1 + l * DD, bl2 + l * DD, cur);
    xl = cur;
  }
  // xl == bufA. P1 -> bufA (in place), P2 -> bufB.
  gemm_pred_mfma<<<mfmaBlocks, 256, 0, stream>>>(
      bufA,
      WTh + (size_t)6 * 16384, WTl + (size_t)6 * 16384,
      WTh + (size_t)7 * 16384, WTl + (size_t)7 * 16384,
      bp1, bufA, bufB);
  edge_out<<<aggBlocks, 256, 0, stream>>>(
      (const float4*)bufA, (const float4*)bufB, offs, srcs_s, eid_s,
      (const float4*)Wp2, bp2, (float*)d_out);
}

// Round 7
// 539.171 us; speedup vs baseline: 1.1864x; 1.1864x over previous
//
#include <hip/hip_runtime.h>

#define NN 50000
#define NE 800000
#define DD 128

typedef __attribute__((ext_vector_type(8))) short short8;
typedef __attribute__((ext_vector_type(4))) float f32x4;

__device__ inline unsigned short f2bf_rne(float f) {
  unsigned u = __float_as_uint(f);
  u += 0x7FFF + ((u >> 16) & 1);
  return (unsigned short)(u >> 16);
}
__device__ inline float bf2f(unsigned short h) {
  return __uint_as_float(((unsigned)h) << 16);
}

// ------------------------------------------------- CSR build: histogram
__global__ __launch_bounds__(256) void hist_dst(const int* __restrict__ dst,
                                                int* __restrict__ cnt) {
  int e = blockIdx.x * 256 + threadIdx.x;
  if (e < NE) atomicAdd(&cnt[dst[e]], 1);
}

// ------------------------------------------------- CSR build: scan (1 block)
__global__ __launch_bounds__(1024) void scan_nodes(const int* __restrict__ cnt,
                                                   int* __restrict__ offs,
                                                   int* __restrict__ cursor) {
  __shared__ int wsum[16];
  __shared__ int wpre[16];
  const int t = threadIdx.x;
  const int lane = t & 63, wv = t >> 6;
  int carry = 0;
  for (int base = 0; base < NN; base += 8192) {
    const int i0 = base + t * 8;
    int4 a = make_int4(0, 0, 0, 0), b = make_int4(0, 0, 0, 0);
    if (i0 + 8 <= NN) {
      a = *(const int4*)(cnt + i0);
      b = *(const int4*)(cnt + i0 + 4);
    } else if (i0 < NN) {
      int tmp[8];
      for (int j = 0; j < 8; ++j) tmp[j] = (i0 + j < NN) ? cnt[i0 + j] : 0;
      a = make_int4(tmp[0], tmp[1], tmp[2], tmp[3]);
      b = make_int4(tmp[4], tmp[5], tmp[6], tmp[7]);
    }
    const int own = a.x + a.y + a.z + a.w + b.x + b.y + b.z + b.w;
    int inc = own;
#pragma unroll
    for (int d = 1; d < 64; d <<= 1) {
      int v = __shfl_up(inc, d, 64);
      if (lane >= d) inc += v;
    }
    if (lane == 63) wsum[wv] = inc;
    __syncthreads();
    if (t < 16) {
      int v = wsum[t];
      int p = v;
#pragma unroll
      for (int d = 1; d < 16; d <<= 1) {
        int u = __shfl_up(p, d, 16);
        if (t >= d) p += u;
      }
      wpre[t] = p - v;
      if (t == 15) wsum[15] = p;
    }
    __syncthreads();
    int run = carry + wpre[wv] + inc - own;
    const int o0 = run,      o1 = o0 + a.x, o2 = o1 + a.y, o3 = o2 + a.z;
    const int o4 = o3 + a.w, o5 = o4 + b.x, o6 = o5 + b.y, o7 = o6 + b.z;
    if (i0 + 8 <= NN) {
      *(int4*)(offs + i0)       = make_int4(o0, o1, o2, o3);
      *(int4*)(offs + i0 + 4)   = make_int4(o4, o5, o6, o7);
      *(int4*)(cursor + i0)     = make_int4(o0, o1, o2, o3);
      *(int4*)(cursor + i0 + 4) = make_int4(o4, o5, o6, o7);
    } else if (i0 < NN) {
      const int o[8] = {o0, o1, o2, o3, o4, o5, o6, o7};
      for (int j = 0; j < 8; ++j)
        if (i0 + j < NN) { offs[i0 + j] = o[j]; cursor[i0 + j] = o[j]; }
    }
    carry += wsum[15];
    __syncthreads();
  }
  if (t == 0) offs[NN] = carry;
}

// ------------------------------------------------- CSR build: fill
__global__ __launch_bounds__(256) void csr_fill(
    const int* __restrict__ src, const int* __restrict__ dst,
    const float* __restrict__ ea, int* __restrict__ cursor,
    int* __restrict__ srcs_s, float* __restrict__ eas_s,
    int* __restrict__ eid_s) {
  int e = blockIdx.x * 256 + threadIdx.x;
  if (e >= NE) return;
  int pos = atomicAdd(&cursor[dst[e]], 1);
  srcs_s[pos] = src[e];
  eas_s[pos] = ea[e];
  eid_s[pos] = e;
}

// ------------------------------------------------- weight prep: transpose + split
// 8 mats [128k][128n] f32 -> WT_hi/WT_lo [g][n][k] bf16
__global__ __launch_bounds__(256) void prep_w(
    const float* __restrict__ Wl1, const float* __restrict__ Wl2,
    const float* __restrict__ Wp1,
    unsigned short* __restrict__ WTh, unsigned short* __restrict__ WTl) {
  int tid = blockIdx.x * 256 + threadIdx.x;  // 8 * 16384
  if (tid >= 8 * 16384) return;
  int g = tid >> 14, idx = tid & 16383;
  int n = idx >> 7, k = idx & 127;
  const float* s;
  if (g < 3) s = Wl1 + (size_t)g * 16384;
  else if (g < 6) s = Wl2 + (size_t)(g - 3) * 16384;
  else s = Wp1 + (size_t)(g - 6) * 16384;
  float v = s[k * 128 + n];
  unsigned short hi = f2bf_rne(v);
  WTh[tid] = hi;
  WTl[tid] = f2bf_rne(v - bf2f(hi));
}

// ------------------------------------------------- per-node aggregation
__global__ __launch_bounds__(256) void aggregate(
    const float* __restrict__ x, const int* __restrict__ offs,
    const int* __restrict__ srcs_s, const float* __restrict__ eas_s,
    const float4* __restrict__ We4, const float4* __restrict__ be4,
    float* __restrict__ out) {
  const int slot = threadIdx.x >> 5, lane = threadIdx.x & 31;
  const int n = blockIdx.x * 8 + slot;
  if (n >= NN) return;
  const float4 wv = We4[lane], bv = be4[lane];
  float4 acc0 = ((const float4*)(x + (size_t)n * DD))[lane];
  float4 acc1 = make_float4(0.f, 0.f, 0.f, 0.f);
  const int beg = offs[n], end = offs[n + 1];
  int i = beg;
  for (; i + 2 <= end; i += 2) {
    const int s0 = srcs_s[i], s1 = srcs_s[i + 1];
    const float a0 = eas_s[i], a1 = eas_s[i + 1];
    const float4 x0 = ((const float4*)(x + (size_t)s0 * DD))[lane];
    const float4 x1 = ((const float4*)(x + (size_t)s1 * DD))[lane];
    acc0.x += fmaxf(fmaf(a0, wv.x, bv.x) + x0.x, 0.f);
    acc0.y += fmaxf(fmaf(a0, wv.y, bv.y) + x0.y, 0.f);
    acc0.z += fmaxf(fmaf(a0, wv.z, bv.z) + x0.z, 0.f);
    acc0.w += fmaxf(fmaf(a0, wv.w, bv.w) + x0.w, 0.f);
    acc1.x += fmaxf(fmaf(a1, wv.x, bv.x) + x1.x, 0.f);
    acc1.y += fmaxf(fmaf(a1, wv.y, bv.y) + x1.y, 0.f);
    acc1.z += fmaxf(fmaf(a1, wv.z, bv.z) + x1.z, 0.f);
    acc1.w += fmaxf(fmaf(a1, wv.w, bv.w) + x1.w, 0.f);
  }
  if (i < end) {
    const int s0 = srcs_s[i];
    const float a0 = eas_s[i];
    const float4 x0 = ((const float4*)(x + (size_t)s0 * DD))[lane];
    acc0.x += fmaxf(fmaf(a0, wv.x, bv.x) + x0.x, 0.f);
    acc0.y += fmaxf(fmaf(a0, wv.y, bv.y) + x0.y, 0.f);
    acc0.z += fmaxf(fmaf(a0, wv.z, bv.z) + x0.z, 0.f);
    acc0.w += fmaxf(fmaf(a0, wv.w, bv.w) + x0.w, 0.f);
  }
  acc0.x += acc1.x; acc0.y += acc1.y; acc0.z += acc1.z; acc0.w += acc1.w;
  ((float4*)(out + (size_t)n * DD))[lane] = acc0;
}

// ------------------------------------------------- GEMM: B resident in registers
// [50000,128] @ [128,128] via split-bf16 MFMA (Ah*Bh + Ah*Bl + Al*Bh).
// Wave w of each block owns column-quarter w (2 col-tiles, B in 64 VGPRs,
// loaded ONCE). Blocks grid-stride over 3125 16-row chunks; per chunk a wave
// issues 8 independent float4 A-loads (full rows), converts, 24 MFMAs.
// INPLACE: the 4 quarter-waves of a block share A rows -> barrier between
// last A-read (pre-MFMA) and stores makes in==out safe.
template <bool RELU, bool HASB, bool INPLACE>
__global__ __launch_bounds__(256) void gemm_breg(
    const float* __restrict__ in,
    const unsigned short* __restrict__ Wh, const unsigned short* __restrict__ Wl,
    const float* __restrict__ bias, float* __restrict__ out) {
  const int t = threadIdx.x;
  const int w = t >> 6, l = t & 63;
  const int lr = l & 15, kg = l >> 4;

  short8 Bh[2][4], Bl[2][4];
#pragma unroll
  for (int ct = 0; ct < 2; ++ct)
#pragma unroll
    for (int ks = 0; ks < 4; ++ks) {
      const size_t bo = (size_t)((w * 2 + ct) * 16 + lr) * DD + ks * 32 + kg * 8;
      Bh[ct][ks] = *(const short8*)(Wh + bo);
      Bl[ct][ks] = *(const short8*)(Wl + bo);
    }
  float bv0 = 0.f, bv1 = 0.f;
  if (HASB) {
    bv0 = bias[(w * 2 + 0) * 16 + lr];
    bv1 = bias[(w * 2 + 1) * 16 + lr];
  }

  for (int c = blockIdx.x; c < NN / 16; c += gridDim.x) {
    const float* ap = in + ((size_t)c * 16 + lr) * DD + kg * 8;
    float va[4][8];
#pragma unroll
    for (int ks = 0; ks < 4; ++ks) {
      *(float4*)&va[ks][0] = *(const float4*)(ap + ks * 32);
      *(float4*)&va[ks][4] = *(const float4*)(ap + ks * 32 + 4);
    }
    short8 ah[4], al[4];
#pragma unroll
    for (int ks = 0; ks < 4; ++ks)
#pragma unroll
      for (int j = 0; j < 8; ++j) {
        unsigned short h = f2bf_rne(va[ks][j]);
        ah[ks][j] = (short)h;
        al[ks][j] = (short)f2bf_rne(va[ks][j] - bf2f(h));
      }
    f32x4 acc[2];
    acc[0] = (f32x4){0.f, 0.f, 0.f, 0.f};
    acc[1] = (f32x4){0.f, 0.f, 0.f, 0.f};
#pragma unroll
    for (int ks = 0; ks < 4; ++ks) {
#pragma unroll
      for (int ct = 0; ct < 2; ++ct) {
        acc[ct] = __builtin_amdgcn_mfma_f32_16x16x32_bf16(ah[ks], Bh[ct][ks], acc[ct], 0, 0, 0);
        acc[ct] = __builtin_amdgcn_mfma_f32_16x16x32_bf16(ah[ks], Bl[ct][ks], acc[ct], 0, 0, 0);
        acc[ct] = __builtin_amdgcn_mfma_f32_16x16x32_bf16(al[ks], Bh[ct][ks], acc[ct], 0, 0, 0);
      }
    }
    if (INPLACE) __syncthreads();
    // C layout: col = lane&15, row = (lane>>4)*4 + q
#pragma unroll
    for (int ct = 0; ct < 2; ++ct) {
      const float bb = ct ? bv1 : bv0;
      const int col = (w * 2 + ct) * 16 + lr;
#pragma unroll
      for (int q4 = 0; q4 < 4; ++q4) {
        float v = acc[ct][q4] + bb;
        if (RELU) v = fmaxf(v, 0.f);
        out[((size_t)c * 16 + kg * 4 + q4) * DD + col] = v;
      }
    }
  }
}

// ------------------------------------------------- final edge pass (node-parallel)
__global__ __launch_bounds__(256) void edge_out(
    const float4* __restrict__ P1_4, const float4* __restrict__ P2_4,
    const int* __restrict__ offs, const int* __restrict__ srcs_s,
    const int* __restrict__ eid_s, const float4* __restrict__ Wp2_4,
    const float* __restrict__ bp2, float* __restrict__ out) {
  const int slot = threadIdx.x >> 5, lane = threadIdx.x & 31;
  const int n = blockIdx.x * 8 + slot;
  if (n >= NN) return;
  const float4 p2 = P2_4[(size_t)n * 32 + lane];
  const float4 w = Wp2_4[lane];
  const float bb = bp2[0];
  const int beg = offs[n], end = offs[n + 1];
  int i = beg;
  for (; i + 2 <= end; i += 2) {
    const int s0 = srcs_s[i], s1 = srcs_s[i + 1];
    const int e0 = eid_s[i], e1 = eid_s[i + 1];
    const float4 q0 = P1_4[(size_t)s0 * 32 + lane];
    const float4 q1 = P1_4[(size_t)s1 * 32 + lane];
    float v0 = fmaxf(q0.x + p2.x, 0.f) * w.x + fmaxf(q0.y + p2.y, 0.f) * w.y
             + fmaxf(q0.z + p2.z, 0.f) * w.z + fmaxf(q0.w + p2.w, 0.f) * w.w;
    float v1 = fmaxf(q1.x + p2.x, 0.f) * w.x + fmaxf(q1.y + p2.y, 0.f) * w.y
             + fmaxf(q1.z + p2.z, 0.f) * w.z + fmaxf(q1.w + p2.w, 0.f) * w.w;
#pragma unroll
    for (int m = 16; m >= 1; m >>= 1) {
      v0 += __shfl_xor(v0, m, 64);
      v1 += __shfl_xor(v1, m, 64);
    }
    if (lane == 0) { out[e0] = v0 + bb; out[e1] = v1 + bb; }
  }
  if (i < end) {
    const int s0 = srcs_s[i];
    const int e0 = eid_s[i];
    const float4 q0 = P1_4[(size_t)s0 * 32 + lane];
    float v0 = fmaxf(q0.x + p2.x, 0.f) * w.x + fmaxf(q0.y + p2.y, 0.f) * w.y
             + fmaxf(q0.z + p2.z, 0.f) * w.z + fmaxf(q0.w + p2.w, 0.f) * w.w;
#pragma unroll
    for (int m = 16; m >= 1; m >>= 1) v0 += __shfl_xor(v0, m, 64);
    if (lane == 0) out[e0] = v0 + bb;
  }
}

// ---------------------------------------------------------------- launch
extern "C" void kernel_launch(void* const* d_in, const int* in_sizes, int n_in,
                              void* d_out, int out_size, void* d_ws, size_t ws_size,
                              hipStream_t stream) {
  const float* x_in = (const float*)d_in[0];
  const float* ea   = (const float*)d_in[1];
  const int*   ei   = (const int*)d_in[2];   // integer inputs arrive as int32
  const float* Wl1 = (const float*)d_in[3];
  const float* bl1 = (const float*)d_in[4];
  const float* Wl2 = (const float*)d_in[5];
  const float* bl2 = (const float*)d_in[6];
  const float* We  = (const float*)d_in[7];
  const float* be  = (const float*)d_in[8];
  const float* Wp1 = (const float*)d_in[9];
  const float* bp1 = (const float*)d_in[10];
  const float* Wp2 = (const float*)d_in[11];
  const float* bp2 = (const float*)d_in[12];
  const int* src = ei;
  const int* dst = ei + NE;

  // workspace layout (~62 MB)
  float* bufA   = (float*)d_ws;                    // NN*DD
  float* bufB   = bufA + (size_t)NN * DD;          // NN*DD
  int*   cnt    = (int*)(bufB + (size_t)NN * DD);  // NN
  int*   offs   = cnt + NN;                        // NN+1
  int*   cursor = offs + NN + 1;                   // NN
  int*   srcs_s = cursor + NN;                     // NE
  float* eas_s  = (float*)(srcs_s + NE);           // NE
  int*   eid_s  = (int*)(eas_s + NE);              // NE
  unsigned short* WTh = (unsigned short*)(eid_s + NE);  // 8*16384 bf16
  unsigned short* WTl = WTh + 8 * 16384;                // 8*16384 bf16

  // CSR build + weight prep (per-launch, deterministic)
  hipMemsetAsync(cnt, 0, NN * sizeof(int), stream);
  hist_dst<<<NE / 256, 256, 0, stream>>>(dst, cnt);
  scan_nodes<<<1, 1024, 0, stream>>>(cnt, offs, cursor);
  csr_fill<<<NE / 256, 256, 0, stream>>>(src, dst, ea, cursor, srcs_s, eas_s, eid_s);
  prep_w<<<(8 * 16384 + 255) / 256, 256, 0, stream>>>(Wl1, Wl2, Wp1, WTh, WTl);

  const int GB = 1024;            // gemm grid
  const int aggBlocks = (NN + 7) / 8;
#define WH(g) (WTh + (size_t)(g) * 16384)
#define WL(g) (WTl + (size_t)(g) * 16384)

  // layer 0: x_in -> bufA -> bufB -> bufA
  aggregate<<<aggBlocks, 256, 0, stream>>>(
      x_in, offs, srcs_s, eas_s, (const float4*)We, (const float4*)be, bufA);
  gemm_breg<true, true, false><<<GB, 256, 0, stream>>>(bufA, WH(0), WL(0), bl1, bufB);
  gemm_breg<true, true, false><<<GB, 256, 0, stream>>>(bufB, WH(3), WL(3), bl2, bufA);
  // layer 1: bufA -> bufB -> bufA -> bufB
  aggregate<<<aggBlocks, 256, 0, stream>>>(
      bufA, offs, srcs_s, eas_s, (const float4*)(We + DD), (const float4*)(be + DD), bufB);
  gemm_breg<true, true, false><<<GB, 256, 0, stream>>>(bufB, WH(1), WL(1), bl1 + DD, bufA);
  gemm_breg<true, true, false><<<GB, 256, 0, stream>>>(bufA, WH(4), WL(4), bl2 + DD, bufB);
  // layer 2: bufB -> bufA -> bufB -> bufA
  aggregate<<<aggBlocks, 256, 0, stream>>>(
      bufB, offs, srcs_s, eas_s, (const float4*)(We + 2 * DD), (const float4*)(be + 2 * DD), bufA);
  gemm_breg<true, true, false><<<GB, 256, 0, stream>>>(bufA, WH(2), WL(2), bl1 + 2 * DD, bufB);
  gemm_breg<true, true, false><<<GB, 256, 0, stream>>>(bufB, WH(5), WL(5), bl2 + 2 * DD, bufA);
  // predictor: xf = bufA. P2 -> bufB, then P1 in-place -> bufA.
  gemm_breg<false, true, false><<<GB, 256, 0, stream>>>(bufA, WH(7), WL(7), bp1, bufB);
  gemm_breg<false, false, true><<<GB, 256, 0, stream>>>(bufA, WH(6), WL(6), (const float*)nullptr, bufA);
  edge_out<<<aggBlocks, 256, 0, stream>>>(
      (const float4*)bufA, (const float4*)bufB, offs, srcs_s, eid_s,
      (const float4*)Wp2, bp2, (float*)d_out);
}